// Round 3
// baseline (404.284 us; speedup 1.0000x reference)
//
#include <hip/hip_runtime.h>

// Problem constants (fixed by reference): B=4, S=2048, DIN=4096, DOUT=4096
#define GM 8192   // M = B*S
#define GN 4096   // N = DOUT
#define GK 4096   // K = DIN

#define BM 128
#define BN 256
#define BK 64             // bytes of K per tile (i8)
#define NTILE (GK / BK)   // 64 K-tiles
#define ABYTES (BM * BK)              // 8192 B per K-tile
#define TILE_LDS (ABYTES + BN * BK)   // 24576 B per K-tile buffer

using int4v = __attribute__((ext_vector_type(4))) int;

// ---------------- fused quantization ----------------
// x path: x_int8 = (int)(x * input_scale)      -- trunc toward zero
// w path: w_int8 = (int)rintf(w * wscale[row]) -- round half-even
__global__ __launch_bounds__(256) void quant_xw_k(
    const float4* __restrict__ x, unsigned int* __restrict__ xq,
    const float4* __restrict__ w, unsigned int* __restrict__ wq,
    const float* __restrict__ wscale, const float* __restrict__ iscale,
    int n4x, int n4tot) {
    const float xs = *iscale;
    const int stride = gridDim.x * blockDim.x;
    for (int i = blockIdx.x * blockDim.x + threadIdx.x; i < n4tot; i += stride) {
        if (i < n4x) {
            float4 v = x[i];
            int q0 = (int)(v.x * xs);
            int q1 = (int)(v.y * xs);
            int q2 = (int)(v.z * xs);
            int q3 = (int)(v.w * xs);
            xq[i] = (unsigned int)(q0 & 0xff)
                  | ((unsigned int)(q1 & 0xff) << 8)
                  | ((unsigned int)(q2 & 0xff) << 16)
                  | ((unsigned int)(q3 & 0xff) << 24);
        } else {
            int j = i - n4x;
            float s = wscale[j >> 10];          // 1024 float4 per 4096-f32 row
            float4 v = w[j];
            int q0 = (int)rintf(v.x * s);
            int q1 = (int)rintf(v.y * s);
            int q2 = (int)rintf(v.z * s);
            int q3 = (int)rintf(v.w * s);
            wq[j] = (unsigned int)(q0 & 0xff)
                  | ((unsigned int)(q1 & 0xff) << 8)
                  | ((unsigned int)(q2 & 0xff) << 16)
                  | ((unsigned int)(q3 & 0xff) << 24);
        }
    }
}

// ---------------- int8 GEMM: 128x256 tile, 8 waves of 64x64 ----------------
// Occupancy-first variant of the verified R1 structure: per-wave registers
// halved (acc[4][4]=64 AGPR, frags 32 VGPR) so __launch_bounds__(512,4)
// fits 4 waves/SIMD = 2 blocks/CU (LDS 72 KiB x2 = 144 <= 160).
// Ledger (identical to R1, 3 GLL/thread/K-tile, depth-3 buffers):
//   iter t: STAGE(t+2 -> buf[(t+2)%3])  (buf held t-1; its reads retired
//           before end-of-(t-1) barrier), ds_read+MFMA tile t from buf[t%3],
//           s_waitcnt vmcnt(3) retires tile t+1 (t+2's 3 stay in flight
//           across the barrier), one s_barrier per K-tile. Never drains.
// Swizzle (verified, conflicts==0): stored slot s of row r holds chunk
//   s ^ ((r>>1)&3); GLL writes linearly so the *source* chunk is permuted:
//   kc = (tid&3)^((tid>>3)&3); reads use pos = ((lane>>4)^((lane>>1)&3))*16.
__global__ __launch_bounds__(512, 4) void qlinear_gemm_i8(
    const signed char* __restrict__ Aq,
    const signed char* __restrict__ Bq,
    const float* __restrict__ bias,
    const float* __restrict__ wscale,
    const float* __restrict__ iscale,
    float* __restrict__ C) {
    __shared__ signed char smem[3 * TILE_LDS];   // 72 KiB

    const int tid  = threadIdx.x;
    const int wave = tid >> 6;
    const int lane = tid & 63;
    const int m0 = blockIdx.x * BM;
    const int n0 = blockIdx.y * BN;
    const int wm = (wave >> 2) * 64;     // {0,64}
    const int wn = (wave & 3) * 64;      // {0,64,128,192}

    int4v acc[4][4];
#pragma unroll
    for (int i = 0; i < 4; ++i)
#pragma unroll
        for (int j = 0; j < 4; ++j)
            acc[i][j] = int4v{0, 0, 0, 0};

    // --- staging: 512 threads cover 128 rows x 64 B per GLL round
    const int kc = ((tid & 3) ^ ((tid >> 3) & 3)) * 16;   // swizzled src chunk
    const signed char* gA = Aq + (size_t)(m0 + (tid >> 2)) * GK + kc;
    const signed char* gB = Bq + (size_t)(n0 + (tid >> 2)) * GK + kc;
    const int dst = tid * 16;                             // linear LDS dest

    // --- LDS fragment read offsets (within one K-tile buffer)
    const int pos = (((lane >> 4) ^ ((lane >> 1) & 3))) * 16;
    const int fAo = (wm + (lane & 15)) * BK + pos;            // + mi*1024
    const int fBo = ABYTES + (wn + (lane & 15)) * BK + pos;   // + ni*1024

#define GLL16(g, l)                                                     \
    __builtin_amdgcn_global_load_lds(                                   \
        (__attribute__((address_space(1))) void*)(void*)(g),            \
        (__attribute__((address_space(3))) void*)(void*)(l), 16, 0, 0)

#define STAGE(kb, soff)                                                 \
    do {                                                                \
        GLL16(gA + (kb), smem + (soff) + dst);                          \
        GLL16(gB + (kb), smem + (soff) + ABYTES + dst);                 \
        GLL16(gB + (size_t)128 * GK + (kb),                             \
              smem + (soff) + ABYTES + 8192 + dst);                     \
    } while (0)

    // --- prologue: stage tiles 0 and 1; retire tile 0 only (vmcnt 3 leaves
    // tile 1's 3 loads in flight), rendezvous.
    STAGE(0, 0);
    STAGE(BK, TILE_LDS);
    asm volatile("s_waitcnt vmcnt(3)" ::: "memory");
    __builtin_amdgcn_s_barrier();
    __builtin_amdgcn_sched_barrier(0);

    int bc = 0;                 // buffer byte-offset of tile t
    int bn2 = TILE_LDS;         // tile t+1
    int bs = 2 * TILE_LDS;      // stage target (tile t+2)
    int kst = 2 * BK;           // k-byte of tile t+2 (wraps: harmless re-read)
    for (int t = 0; t < NTILE; ++t) {
        STAGE(kst, bs);                     // tile t+2 -> buffer of tile t-1
        __builtin_amdgcn_sched_barrier(0);  // pin GLL issue before reads

        const signed char* fA = smem + bc + fAo;
        const signed char* fB = smem + bc + fBo;
        int4v a[4], b[4];
#pragma unroll
        for (int i = 0; i < 4; ++i)
            a[i] = *(const int4v*)(fA + i * 1024);
#pragma unroll
        for (int j = 0; j < 4; ++j)
            b[j] = *(const int4v*)(fB + j * 1024);

        __builtin_amdgcn_s_setprio(1);
#pragma unroll
        for (int mi = 0; mi < 4; ++mi)
#pragma unroll
            for (int ni = 0; ni < 4; ++ni)
                acc[mi][ni] = __builtin_amdgcn_mfma_i32_16x16x64_i8(
                    a[mi], b[ni], acc[mi][ni], 0, 0, 0);
        __builtin_amdgcn_s_setprio(0);

        // retire tile t+1's 3 loads; tile t+2's 3 stay in flight
        asm volatile("s_waitcnt vmcnt(3)" ::: "memory");
        __builtin_amdgcn_s_barrier();
        __builtin_amdgcn_sched_barrier(0);

        int tmp = bc; bc = bn2; bn2 = bs; bs = tmp;
        kst += BK; if (kst >= GK) kst = 0;
    }

    // --- epilogue: C/D layout col=lane&15, row=(lane>>4)*4+reg
    const float isc = *iscale;
#pragma unroll
    for (int ni = 0; ni < 4; ++ni) {
        const int col = n0 + wn + ni * 16 + (lane & 15);
        const float bs_ = bias[col];
        const float inv = 1.0f / (wscale[col] * isc);
#pragma unroll
        for (int mi = 0; mi < 4; ++mi) {
            const int row0 = m0 + wm + mi * 16 + (lane >> 4) * 4;
#pragma unroll
            for (int r = 0; r < 4; ++r) {
                C[(size_t)(row0 + r) * GN + col] =
                    ((float)acc[mi][ni][r] + bs_) * inv;
            }
        }
    }
#undef STAGE
#undef GLL16
}

extern "C" void kernel_launch(void* const* d_in, const int* in_sizes, int n_in,
                              void* d_out, int out_size, void* d_ws, size_t ws_size,
                              hipStream_t stream) {
    const float* x      = (const float*)d_in[0];  // (4,2048,4096)
    const float* w      = (const float*)d_in[1];  // (4096,4096)
    const float* bias   = (const float*)d_in[2];  // (4096,)
    const float* wscale = (const float*)d_in[3];  // (4096,)
    const float* iscale = (const float*)d_in[4];  // (1,)
    float* out = (float*)d_out;

    signed char* xq = (signed char*)d_ws;                       // 32 MiB
    signed char* wq = xq + (size_t)GM * GK;                     // 16 MiB

    const int n4x = GM * GK / 4;
    const int n4w = GN * GK / 4;
    quant_xw_k<<<3072, 256, 0, stream>>>((const float4*)x, (unsigned int*)xq,
                                         (const float4*)w, (unsigned int*)wq,
                                         wscale, iscale, n4x, n4x + n4w);

    dim3 grid(GM / BM, GN / BN);   // 64 x 16 = 1024 blocks of 512 threads
    qlinear_gemm_i8<<<grid, 512, 0, stream>>>(xq, wq, bias, wscale, iscale, out);
}